// Round 9
// baseline (414.399 us; speedup 1.0000x reference)
//
#include <hip/hip_runtime.h>
#include <math.h>

#define N_NODES 50000
#define N_EDGES 600000
#define HID 128
#define NLAYERS 4
#define NODE_IN 16
#define EDGE_IN 8
#define LN_EPS 1e-5f
#define SCAN_BLOCKS ((N_NODES + 255) / 256)

typedef short bf16x8 __attribute__((ext_vector_type(8)));
typedef float f32x4 __attribute__((ext_vector_type(4)));

__device__ __forceinline__ float b2f(unsigned short u) {
    union { unsigned int i; float f; } v; v.i = ((unsigned int)u) << 16; return v.f;
}
__device__ __forceinline__ unsigned short f2b(float x) {
    union { float f; unsigned int i; } v; v.f = x;
    unsigned int b = v.i + 0x7FFFu + ((v.i >> 16) & 1u);
    return (unsigned short)(b >> 16);
}

// ---------------- edge_index dtype detection (int32 vs int64) ----------------
__global__ void detect_i64(const int* ei, int* flag) {
    __shared__ int nz;
    if (threadIdx.x == 0) nz = 0;
    __syncthreads();
    int acc = 0;
    for (int i = threadIdx.x; i < 1024; i += blockDim.x)
        if (ei[2 * i + 1] != 0) acc = 1;
    if (acc) atomicOr(&nz, 1);
    __syncthreads();
    if (threadIdx.x == 0) *flag = (nz == 0) ? 1 : 0;
}

__device__ __forceinline__ int edge_src(const void* ei, int f, int e) {
    if (f) return (int)((const long long*)ei)[e];
    return ((const int*)ei)[e];
}
__device__ __forceinline__ int edge_dst(const void* ei, int f, int e) {
    if (f) return (int)((const long long*)ei)[N_EDGES + e];
    return ((const int*)ei)[N_EDGES + e];
}

// ---------------- CSR build ----------------
__global__ void hist_k(const void* ei, const int* flag, int* cursor) {
    int e = blockIdx.x * blockDim.x + threadIdx.x;
    if (e >= N_EDGES) return;
    int f = *flag;
    atomicAdd(&cursor[edge_dst(ei, f, e)], 1);
}

__global__ void scan1_k(const int* __restrict__ cursor, int* __restrict__ locex,
                        int* __restrict__ partials) {
    __shared__ int sd[256];
    int t = threadIdx.x, i = blockIdx.x * 256 + t;
    int v = (i < N_NODES) ? cursor[i] : 0;
    sd[t] = v;
    __syncthreads();
    for (int off = 1; off < 256; off <<= 1) {
        int x = (t >= off) ? sd[t - off] : 0;
        __syncthreads();
        sd[t] += x;
        __syncthreads();
    }
    if (i < N_NODES) locex[i] = sd[t] - v;
    if (t == 255) partials[blockIdx.x] = sd[255];
}

__global__ void scan2_k(int* partials) {
    __shared__ int sd[256];
    int t = threadIdx.x;
    int v = (t < SCAN_BLOCKS) ? partials[t] : 0;
    sd[t] = v;
    __syncthreads();
    for (int off = 1; off < 256; off <<= 1) {
        int x = (t >= off) ? sd[t - off] : 0;
        __syncthreads();
        sd[t] += x;
        __syncthreads();
    }
    if (t < SCAN_BLOCKS) partials[t] = sd[t] - v;
    if (t == 255) partials[SCAN_BLOCKS] = sd[255];
}

__global__ void scan3_k(int* __restrict__ row_ptr, int* __restrict__ cursor,
                        const int* __restrict__ partials) {
    int i = blockIdx.x * 256 + threadIdx.x;
    if (i < N_NODES) {
        int r = row_ptr[i] + partials[blockIdx.x];
        row_ptr[i] = r;
        cursor[i] = r;
    }
    if (i == N_NODES) row_ptr[N_NODES] = partials[SCAN_BLOCKS];
}

__global__ void place_k(const void* ei, const int* flag, int* cursor,
                        int* sorted_src, int* sorted_eid) {
    int e = blockIdx.x * blockDim.x + threadIdx.x;
    if (e >= N_EDGES) return;
    int f = *flag;
    int s = edge_src(ei, f, e);
    int d = edge_dst(ei, f, e);
    int pos = atomicAdd(&cursor[d], 1);
    sorted_src[pos] = s;
    sorted_eid[pos] = e;
}

// ---------------- weight precompute (f32 epilogue constants) ----------------
__global__ void precompute_k(const float* __restrict__ edge_w, const float* __restrict__ edge_b,
                             const float* __restrict__ ledge_w, const float* __restrict__ ledge_b,
                             const float* __restrict__ lnode_b,
                             const float* __restrict__ adm_w, const float* __restrict__ adm_b,
                             float* __restrict__ M, float* __restrict__ cb,
                             float* __restrict__ v, float* __restrict__ cgate) {
    int t = blockIdx.x * 256 + threadIdx.x;
    if (t < 4096) {
        int l = t >> 10, k = (t >> 7) & 7, ch = t & 127;
        const float* lw = ledge_w + (size_t)l * HID * HID;
        float a = 0.f;
        for (int j = 0; j < HID; ++j) a += edge_w[k * HID + j] * lw[j * HID + ch];
        M[t] = a;
    } else if (t < 4608) {
        int u = t - 4096;
        int l = u >> 7, ch = u & 127;
        const float* lw = ledge_w + (size_t)l * HID * HID;
        float a = ledge_b[l * HID + ch] + lnode_b[l * HID + ch];
        for (int j = 0; j < HID; ++j) a += edge_b[j] * lw[j * HID + ch];
        cb[u] = a;
    } else if (t < 4640) {
        int u = t - 4608;
        int l = u >> 3, k = u & 7;
        float a = 0.f;
        for (int j = 0; j < HID; ++j) a += edge_w[k * HID + j] * adm_w[l * HID + j];
        v[u] = a;
    } else if (t < 4644) {
        int l = t - 4640;
        float a = adm_b[l];
        for (int j = 0; j < HID; ++j) a += edge_b[j] * adm_w[l * HID + j];
        cgate[l] = a;
    }
}

// ---- W^T bf16: Wt16[l][n][k] = bf16(lnode_w[l][k][n]) (B-operand, k-contig) --
__global__ void convertw_k(const float* __restrict__ lnode_w, unsigned short* __restrict__ Wt16) {
    int idx = blockIdx.x * 256 + threadIdx.x;
    if (idx >= NLAYERS * HID * HID) return;
    int l = idx >> 14, r = idx & 16383, n = r >> 7, k = r & 127;
    Wt16[idx] = f2b(lnode_w[(size_t)l * HID * HID + k * HID + n]);
}

// ---------------- reorder + gates: thread per sorted position ----------------
__global__ __launch_bounds__(256) void reorder_k(
    const int* __restrict__ sorted_eid, const float* __restrict__ edge_attr,
    const float* __restrict__ vw, const float* __restrict__ cgate,
    float* __restrict__ ea_sorted, float* __restrict__ y_sorted) {
    __shared__ float sv[36];
    if (threadIdx.x < 32) sv[threadIdx.x] = vw[threadIdx.x];
    else if (threadIdx.x < 36) sv[threadIdx.x] = cgate[threadIdx.x - 32];
    __syncthreads();
    int p = blockIdx.x * 256 + threadIdx.x;
    if (p >= N_EDGES) return;
    int eid = sorted_eid[p];
    float4 a0 = ((const float4*)edge_attr)[(size_t)eid * 2];
    float4 a1 = ((const float4*)edge_attr)[(size_t)eid * 2 + 1];
    ((float4*)ea_sorted)[(size_t)p * 2] = a0;
    ((float4*)ea_sorted)[(size_t)p * 2 + 1] = a1;
#pragma unroll
    for (int l = 0; l < NLAYERS; ++l) {
        const float* vl = &sv[l * 8];
        float t = sv[32 + l];
        t += a0.x * vl[0] + a0.y * vl[1] + a0.z * vl[2] + a0.w * vl[3];
        t += a1.x * vl[4] + a1.y * vl[5] + a1.z * vl[6] + a1.w * vl[7];
        y_sorted[(size_t)l * N_EDGES + p] = 1.0f / (1.0f + __expf(-t));
    }
}

// ---------------- per-node edge stats: pure streaming, wave per node ---------
__global__ __launch_bounds__(256) void node_stats_k(
    const int* __restrict__ row_ptr, const float* __restrict__ ea_sorted,
    const float* __restrict__ y_sorted,
    float* __restrict__ agg8, float* __restrict__ sy_arr) {
    int lane = threadIdx.x & 63;
    int n = (blockIdx.x * 256 + threadIdx.x) >> 6;
    int es = lane >> 3, k = lane & 7;
    int ps = row_ptr[n], pe = row_ptr[n + 1];
    float a0 = 0.f, a1 = 0.f, a2 = 0.f, a3 = 0.f;
    float s0 = 0.f, s1 = 0.f, s2 = 0.f, s3 = 0.f;
    for (int p = ps + es; p < pe; p += 8) {
        float ea = ea_sorted[(size_t)p * EDGE_IN + k];
        float y0 = y_sorted[(size_t)0 * N_EDGES + p];
        float y1 = y_sorted[(size_t)1 * N_EDGES + p];
        float y2 = y_sorted[(size_t)2 * N_EDGES + p];
        float y3 = y_sorted[(size_t)3 * N_EDGES + p];
        a0 += y0 * ea; a1 += y1 * ea; a2 += y2 * ea; a3 += y3 * ea;
        s0 += y0; s1 += y1; s2 += y2; s3 += y3;
    }
#pragma unroll
    for (int m = 8; m <= 32; m <<= 1) {
        a0 += __shfl_xor(a0, m, 64); a1 += __shfl_xor(a1, m, 64);
        a2 += __shfl_xor(a2, m, 64); a3 += __shfl_xor(a3, m, 64);
        s0 += __shfl_xor(s0, m, 64); s1 += __shfl_xor(s1, m, 64);
        s2 += __shfl_xor(s2, m, 64); s3 += __shfl_xor(s3, m, 64);
    }
    if (lane < 8) {
        agg8[((size_t)0 * N_NODES + n) * 8 + k] = a0;
        agg8[((size_t)1 * N_NODES + n) * 8 + k] = a1;
        agg8[((size_t)2 * N_NODES + n) * 8 + k] = a2;
        agg8[((size_t)3 * N_NODES + n) * 8 + k] = a3;
    }
    if (lane == 0) {
        sy_arr[(size_t)0 * N_NODES + n] = s0;
        sy_arr[(size_t)1 * N_NODES + n] = s1;
        sy_arr[(size_t)2 * N_NODES + n] = s2;
        sy_arr[(size_t)3 * N_NODES + n] = s3;
    }
}

// ---------------- h0 = x @ node_w + node_b  (f32 + bf16 copies) --------------
__global__ void node_encode_k(const float* __restrict__ x, const float* __restrict__ nw,
                              const float* __restrict__ nb, float* __restrict__ h,
                              unsigned short* __restrict__ h16) {
    int idx = blockIdx.x * 256 + threadIdx.x;
    if (idx >= N_NODES * HID) return;
    int n = idx >> 7, c = idx & 127;
    float acc = nb[c];
#pragma unroll
    for (int k = 0; k < NODE_IN; ++k) acc += x[n * NODE_IN + k] * nw[k * HID + c];
    h[idx] = acc;
    h16[idx] = f2b(acc);
}

// ---------------- pure MFMA GEMM: hn16 = bf16(h16 @ W)  (no bias) ------------
// 16 nodes/block, 4 waves; wave w owns column tiles {2w, 2w+1}.
__global__ __launch_bounds__(256) void mfma_hn_k(
    const unsigned short* __restrict__ h16, const unsigned short* __restrict__ Wt16,
    unsigned short* __restrict__ hn16) {
    const int tid = threadIdx.x;
    const int w = tid >> 6, lane = tid & 63;
    const int g = lane >> 4, c = lane & 15;
    const int nbase = blockIdx.x * 16;
    const int cf0 = w * 2;

    bf16x8 afrag[4];
#pragma unroll
    for (int kc = 0; kc < 4; ++kc)
        afrag[kc] = *(const bf16x8*)(h16 + (size_t)(nbase + c) * HID + kc * 32 + g * 8);

    f32x4 acc[2];
#pragma unroll
    for (int t = 0; t < 2; ++t) {
        acc[t] = (f32x4){0.f, 0.f, 0.f, 0.f};
        const unsigned short* wp = Wt16 + (size_t)((cf0 + t) * 16 + c) * HID + g * 8;
#pragma unroll
        for (int kc = 0; kc < 4; ++kc) {
            bf16x8 bfrag = *(const bf16x8*)(wp + kc * 32);
            acc[t] = __builtin_amdgcn_mfma_f32_16x16x32_bf16(afrag[kc], bfrag, acc[t], 0, 0, 0);
        }
    }
#pragma unroll
    for (int t = 0; t < 2; ++t)
#pragma unroll
        for (int r = 0; r < 4; ++r)
            hn16[(size_t)(nbase + 4 * g + r) * HID + (cf0 + t) * 16 + c] = f2b(acc[t][r]);
}

// ---------------- fused gather + correction + LN + relu + residual -----------
// wave per node (exact grid). acc = sum y*hn16[src]; then + sy*cb + agg8@M;
// LayerNorm over the full wave (lane owns ch {2*lane, 2*lane+1}); relu;
// h_out = h_in + relu(...); writes f32 + bf16.
__global__ __launch_bounds__(256) void gather_ln_k(
    const int* __restrict__ row_ptr, const int* __restrict__ sorted_src,
    const float* __restrict__ y_l, const unsigned short* __restrict__ hn16,
    const float* __restrict__ M_l, const float* __restrict__ cb_l,
    const float* __restrict__ agg8_l, const float* __restrict__ sy_l,
    const float* __restrict__ gm, const float* __restrict__ bt,
    const float* __restrict__ h_in, float* __restrict__ h_out,
    unsigned short* __restrict__ h16_out) {
    int lane = threadIdx.x & 63;
    int n = (blockIdx.x * 256 + threadIdx.x) >> 6;
    int ps = row_ptr[n], pe = row_ptr[n + 1];
    float a0 = 0.f, a1 = 0.f;
    int p = ps;
    for (; p + 7 < pe; p += 8) {
        int s[8];
        float y[8];
        unsigned int v[8];
#pragma unroll
        for (int i = 0; i < 8; ++i) { s[i] = sorted_src[p + i]; y[i] = y_l[p + i]; }
#pragma unroll
        for (int i = 0; i < 8; ++i)
            v[i] = *(const unsigned int*)(hn16 + (size_t)s[i] * HID + lane * 2);
#pragma unroll
        for (int i = 0; i < 8; ++i) {
            a0 += y[i] * b2f((unsigned short)v[i]);
            a1 += y[i] * b2f((unsigned short)(v[i] >> 16));
        }
    }
    for (; p + 3 < pe; p += 4) {
        int s[4];
        float y[4];
        unsigned int v[4];
#pragma unroll
        for (int i = 0; i < 4; ++i) { s[i] = sorted_src[p + i]; y[i] = y_l[p + i]; }
#pragma unroll
        for (int i = 0; i < 4; ++i)
            v[i] = *(const unsigned int*)(hn16 + (size_t)s[i] * HID + lane * 2);
#pragma unroll
        for (int i = 0; i < 4; ++i) {
            a0 += y[i] * b2f((unsigned short)v[i]);
            a1 += y[i] * b2f((unsigned short)(v[i] >> 16));
        }
    }
    for (; p < pe; ++p) {
        float y = y_l[p];
        unsigned int v = *(const unsigned int*)(hn16 + (size_t)sorted_src[p] * HID + lane * 2);
        a0 += y * b2f((unsigned short)v);
        a1 += y * b2f((unsigned short)(v >> 16));
    }

    // correction: + sy*cb + agg8 @ M  (lane channels c0=2*lane, c1=2*lane+1)
    int c0 = lane * 2;
    float sy = sy_l[n];
    float4 t0 = ((const float4*)agg8_l)[(size_t)n * 2];
    float4 t1 = ((const float4*)agg8_l)[(size_t)n * 2 + 1];
    float a8[8] = {t0.x, t0.y, t0.z, t0.w, t1.x, t1.y, t1.z, t1.w};
    float2 cb2 = *(const float2*)&cb_l[c0];
    a0 += sy * cb2.x;
    a1 += sy * cb2.y;
#pragma unroll
    for (int k = 0; k < 8; ++k) {
        float2 m2 = *(const float2*)&M_l[k * HID + c0];
        a0 += a8[k] * m2.x;
        a1 += a8[k] * m2.y;
    }

    // LayerNorm across the wave (128 channels)
    float s = a0 + a1;
    float q = a0 * a0 + a1 * a1;
#pragma unroll
    for (int m = 1; m <= 32; m <<= 1) {
        s += __shfl_xor(s, m, 64);
        q += __shfl_xor(q, m, 64);
    }
    float mean = s * (1.0f / HID);
    float var = q * (1.0f / HID) - mean * mean;
    float rstd = rsqrtf(var + LN_EPS);

    float2 g2 = *(const float2*)&gm[c0];
    float2 b2 = *(const float2*)&bt[c0];
    float2 hi = *(const float2*)&h_in[(size_t)n * HID + c0];
    float o0 = hi.x + fmaxf((a0 - mean) * rstd * g2.x + b2.x, 0.f);
    float o1 = hi.y + fmaxf((a1 - mean) * rstd * g2.y + b2.y, 0.f);
    *(float2*)&h_out[(size_t)n * HID + c0] = make_float2(o0, o1);
    ((unsigned int*)h16_out)[(size_t)n * 64 + lane] =
        ((unsigned int)f2b(o1) << 16) | f2b(o0);
}

extern "C" void kernel_launch(void* const* d_in, const int* in_sizes, int n_in,
                              void* d_out, int out_size, void* d_ws, size_t ws_size,
                              hipStream_t stream) {
    const float* x         = (const float*)d_in[0];
    const void*  ei        = d_in[1];
    const float* edge_attr = (const float*)d_in[2];
    const float* node_w    = (const float*)d_in[3];
    const float* node_b    = (const float*)d_in[4];
    const float* edge_w    = (const float*)d_in[5];
    const float* edge_b    = (const float*)d_in[6];
    const float* lnode_w   = (const float*)d_in[7];
    const float* lnode_b   = (const float*)d_in[8];
    const float* ledge_w   = (const float*)d_in[9];
    const float* ledge_b   = (const float*)d_in[10];
    const float* adm_w     = (const float*)d_in[11];
    const float* adm_b     = (const float*)d_in[12];
    const float* gamma     = (const float*)d_in[13];
    const float* beta      = (const float*)d_in[14];
    float* h = (float*)d_out;

    char* wp = (char*)d_ws;
    auto alloc = [&](size_t bytes) -> void* {
        void* p = (void*)wp;
        wp += (bytes + 255) & ~(size_t)255;
        return p;
    };
    int*            flag       = (int*)alloc(256);
    int*            cursor     = (int*)alloc(sizeof(int) * N_NODES);
    int*            row_ptr    = (int*)alloc(sizeof(int) * (N_NODES + 1));
    int*            partials   = (int*)alloc(sizeof(int) * (SCAN_BLOCKS + 1));
    int*            sorted_src = (int*)alloc(sizeof(int) * N_EDGES);
    int*            sorted_eid = (int*)alloc(sizeof(int) * N_EDGES);
    float*          ea_sorted  = (float*)alloc(sizeof(float) * (size_t)N_EDGES * EDGE_IN);
    float*          y_sorted   = (float*)alloc(sizeof(float) * NLAYERS * N_EDGES);
    float*          agg8       = (float*)alloc(sizeof(float) * NLAYERS * N_NODES * 8);
    float*          sy_arr     = (float*)alloc(sizeof(float) * NLAYERS * N_NODES);
    float*          Mw         = (float*)alloc(sizeof(float) * NLAYERS * 8 * HID);
    float*          cbw        = (float*)alloc(sizeof(float) * NLAYERS * HID);
    float*          vw         = (float*)alloc(sizeof(float) * NLAYERS * 8);
    float*          cgate      = (float*)alloc(sizeof(float) * NLAYERS);
    float*          hbuf       = (float*)alloc(sizeof(float) * (size_t)N_NODES * HID);
    unsigned short* h16        = (unsigned short*)alloc(sizeof(short) * (size_t)N_NODES * HID);
    unsigned short* hn16       = (unsigned short*)alloc(sizeof(short) * (size_t)N_NODES * HID);
    unsigned short* Wt16       = (unsigned short*)alloc(sizeof(short) * NLAYERS * HID * HID);
    (void)ws_size; (void)in_sizes; (void)n_in; (void)out_size;

    hipMemsetAsync(cursor, 0, sizeof(int) * N_NODES, stream);
    detect_i64<<<1, 256, 0, stream>>>((const int*)ei, flag);
    hist_k<<<(N_EDGES + 255) / 256, 256, 0, stream>>>(ei, flag, cursor);
    scan1_k<<<SCAN_BLOCKS, 256, 0, stream>>>(cursor, row_ptr, partials);
    scan2_k<<<1, 256, 0, stream>>>(partials);
    scan3_k<<<SCAN_BLOCKS, 256, 0, stream>>>(row_ptr, cursor, partials);
    place_k<<<(N_EDGES + 255) / 256, 256, 0, stream>>>(ei, flag, cursor, sorted_src, sorted_eid);
    precompute_k<<<19, 256, 0, stream>>>(edge_w, edge_b, ledge_w, ledge_b, lnode_b,
                                         adm_w, adm_b, Mw, cbw, vw, cgate);
    convertw_k<<<(NLAYERS * HID * HID + 255) / 256, 256, 0, stream>>>(lnode_w, Wt16);
    reorder_k<<<(N_EDGES + 255) / 256, 256, 0, stream>>>(sorted_eid, edge_attr,
                                                         vw, cgate, ea_sorted, y_sorted);
    node_stats_k<<<N_NODES / 4, 256, 0, stream>>>(row_ptr, ea_sorted, y_sorted,
                                                  agg8, sy_arr);
    node_encode_k<<<(N_NODES * HID + 255) / 256, 256, 0, stream>>>(x, node_w, node_b, h, h16);

    float* hin = h;
    float* hout = hbuf;
    for (int l = 0; l < NLAYERS; ++l) {
        mfma_hn_k<<<N_NODES / 16, 256, 0, stream>>>(
            h16, Wt16 + (size_t)l * HID * HID, hn16);
        gather_ln_k<<<N_NODES / 4, 256, 0, stream>>>(
            row_ptr, sorted_src, y_sorted + (size_t)l * N_EDGES, hn16,
            Mw + (size_t)l * 8 * HID, cbw + (size_t)l * HID,
            agg8 + (size_t)l * N_NODES * 8, sy_arr + (size_t)l * N_NODES,
            gamma + (size_t)l * HID, beta + (size_t)l * HID,
            hin, hout, h16);
        float* t = hin; hin = hout; hout = t;
    }
    // NLAYERS even -> final f32 result lands in d_out
}

// Round 10
// 377.784 us; speedup vs baseline: 1.0969x; 1.0969x over previous
//
#include <hip/hip_runtime.h>
#include <math.h>

#define N_NODES 50000
#define N_EDGES 600000
#define HID 128
#define NLAYERS 4
#define NODE_IN 16
#define EDGE_IN 8
#define LN_EPS 1e-5f
#define SCAN_BLOCKS ((N_NODES + 255) / 256)

typedef short bf16x8 __attribute__((ext_vector_type(8)));
typedef float f32x4 __attribute__((ext_vector_type(4)));

__device__ __forceinline__ float b2f(unsigned short u) {
    union { unsigned int i; float f; } v; v.i = ((unsigned int)u) << 16; return v.f;
}
__device__ __forceinline__ unsigned short f2b(float x) {
    union { float f; unsigned int i; } v; v.f = x;
    unsigned int b = v.i + 0x7FFFu + ((v.i >> 16) & 1u);
    return (unsigned short)(b >> 16);
}

// ---------------- edge_index dtype detection (int32 vs int64) ----------------
__global__ void detect_i64(const int* ei, int* flag) {
    __shared__ int nz;
    if (threadIdx.x == 0) nz = 0;
    __syncthreads();
    int acc = 0;
    for (int i = threadIdx.x; i < 1024; i += blockDim.x)
        if (ei[2 * i + 1] != 0) acc = 1;
    if (acc) atomicOr(&nz, 1);
    __syncthreads();
    if (threadIdx.x == 0) *flag = (nz == 0) ? 1 : 0;
}

__device__ __forceinline__ int edge_src(const void* ei, int f, int e) {
    if (f) return (int)((const long long*)ei)[e];
    return ((const int*)ei)[e];
}
__device__ __forceinline__ int edge_dst(const void* ei, int f, int e) {
    if (f) return (int)((const long long*)ei)[N_EDGES + e];
    return ((const int*)ei)[N_EDGES + e];
}

// ---------------- CSR build ----------------
__global__ void hist_k(const void* ei, const int* flag, int* cursor) {
    int e = blockIdx.x * blockDim.x + threadIdx.x;
    if (e >= N_EDGES) return;
    int f = *flag;
    atomicAdd(&cursor[edge_dst(ei, f, e)], 1);
}

__global__ void scan1_k(const int* __restrict__ cursor, int* __restrict__ locex,
                        int* __restrict__ partials) {
    __shared__ int sd[256];
    int t = threadIdx.x, i = blockIdx.x * 256 + t;
    int v = (i < N_NODES) ? cursor[i] : 0;
    sd[t] = v;
    __syncthreads();
    for (int off = 1; off < 256; off <<= 1) {
        int x = (t >= off) ? sd[t - off] : 0;
        __syncthreads();
        sd[t] += x;
        __syncthreads();
    }
    if (i < N_NODES) locex[i] = sd[t] - v;
    if (t == 255) partials[blockIdx.x] = sd[255];
}

__global__ void scan2_k(int* partials) {
    __shared__ int sd[256];
    int t = threadIdx.x;
    int v = (t < SCAN_BLOCKS) ? partials[t] : 0;
    sd[t] = v;
    __syncthreads();
    for (int off = 1; off < 256; off <<= 1) {
        int x = (t >= off) ? sd[t - off] : 0;
        __syncthreads();
        sd[t] += x;
        __syncthreads();
    }
    if (t < SCAN_BLOCKS) partials[t] = sd[t] - v;
    if (t == 255) partials[SCAN_BLOCKS] = sd[255];
}

__global__ void scan3_k(int* __restrict__ row_ptr, int* __restrict__ cursor,
                        const int* __restrict__ partials) {
    int i = blockIdx.x * 256 + threadIdx.x;
    if (i < N_NODES) {
        int r = row_ptr[i] + partials[blockIdx.x];
        row_ptr[i] = r;
        cursor[i] = r;
    }
    if (i == N_NODES) row_ptr[N_NODES] = partials[SCAN_BLOCKS];
}

__global__ void place_k(const void* ei, const int* flag, int* cursor,
                        int* sorted_src, int* sorted_eid) {
    int e = blockIdx.x * blockDim.x + threadIdx.x;
    if (e >= N_EDGES) return;
    int f = *flag;
    int s = edge_src(ei, f, e);
    int d = edge_dst(ei, f, e);
    int pos = atomicAdd(&cursor[d], 1);
    sorted_src[pos] = s;
    sorted_eid[pos] = e;
}

// ------- merged weight precompute + W^T bf16 conversion (one dispatch) -------
// t < 4096: M; < 4608: cb; < 4640: v; < 4644: cgate; [4864, 4864+65536): Wt16.
__global__ void precomp_all_k(const float* __restrict__ edge_w, const float* __restrict__ edge_b,
                              const float* __restrict__ ledge_w, const float* __restrict__ ledge_b,
                              const float* __restrict__ lnode_b, const float* __restrict__ lnode_w,
                              const float* __restrict__ adm_w, const float* __restrict__ adm_b,
                              float* __restrict__ M, float* __restrict__ cb,
                              float* __restrict__ v, float* __restrict__ cgate,
                              unsigned short* __restrict__ Wt16) {
    int t = blockIdx.x * 256 + threadIdx.x;
    if (t < 4096) {
        int l = t >> 10, k = (t >> 7) & 7, ch = t & 127;
        const float* lw = ledge_w + (size_t)l * HID * HID;
        float a = 0.f;
        for (int j = 0; j < HID; ++j) a += edge_w[k * HID + j] * lw[j * HID + ch];
        M[t] = a;
    } else if (t < 4608) {
        int u = t - 4096;
        int l = u >> 7, ch = u & 127;
        const float* lw = ledge_w + (size_t)l * HID * HID;
        float a = ledge_b[l * HID + ch] + lnode_b[l * HID + ch];
        for (int j = 0; j < HID; ++j) a += edge_b[j] * lw[j * HID + ch];
        cb[u] = a;
    } else if (t < 4640) {
        int u = t - 4608;
        int l = u >> 3, k = u & 7;
        float a = 0.f;
        for (int j = 0; j < HID; ++j) a += edge_w[k * HID + j] * adm_w[l * HID + j];
        v[u] = a;
    } else if (t < 4644) {
        int l = t - 4640;
        float a = adm_b[l];
        for (int j = 0; j < HID; ++j) a += edge_b[j] * adm_w[l * HID + j];
        cgate[l] = a;
    } else if (t >= 4864 && t < 4864 + NLAYERS * HID * HID) {
        int idx = t - 4864;
        int l = idx >> 14, r = idx & 16383, n = r >> 7, k = r & 127;
        Wt16[idx] = f2b(lnode_w[(size_t)l * HID * HID + k * HID + n]);
    }
}

// ---------------- reorder + gates: thread per sorted position ----------------
__global__ __launch_bounds__(256) void reorder_k(
    const int* __restrict__ sorted_eid, const float* __restrict__ edge_attr,
    const float* __restrict__ vw, const float* __restrict__ cgate,
    float* __restrict__ ea_sorted, float* __restrict__ y_sorted) {
    __shared__ float sv[36];
    if (threadIdx.x < 32) sv[threadIdx.x] = vw[threadIdx.x];
    else if (threadIdx.x < 36) sv[threadIdx.x] = cgate[threadIdx.x - 32];
    __syncthreads();
    int p = blockIdx.x * 256 + threadIdx.x;
    if (p >= N_EDGES) return;
    int eid = sorted_eid[p];
    float4 a0 = ((const float4*)edge_attr)[(size_t)eid * 2];
    float4 a1 = ((const float4*)edge_attr)[(size_t)eid * 2 + 1];
    ((float4*)ea_sorted)[(size_t)p * 2] = a0;
    ((float4*)ea_sorted)[(size_t)p * 2 + 1] = a1;
#pragma unroll
    for (int l = 0; l < NLAYERS; ++l) {
        const float* vl = &sv[l * 8];
        float t = sv[32 + l];
        t += a0.x * vl[0] + a0.y * vl[1] + a0.z * vl[2] + a0.w * vl[3];
        t += a1.x * vl[4] + a1.y * vl[5] + a1.z * vl[6] + a1.w * vl[7];
        y_sorted[(size_t)l * N_EDGES + p] = 1.0f / (1.0f + __expf(-t));
    }
}

// ---------------- per-node edge stats: pure streaming, wave per node ---------
__global__ __launch_bounds__(256) void node_stats_k(
    const int* __restrict__ row_ptr, const float* __restrict__ ea_sorted,
    const float* __restrict__ y_sorted,
    float* __restrict__ agg8, float* __restrict__ sy_arr) {
    int lane = threadIdx.x & 63;
    int n = (blockIdx.x * 256 + threadIdx.x) >> 6;
    int es = lane >> 3, k = lane & 7;
    int ps = row_ptr[n], pe = row_ptr[n + 1];
    float a0 = 0.f, a1 = 0.f, a2 = 0.f, a3 = 0.f;
    float s0 = 0.f, s1 = 0.f, s2 = 0.f, s3 = 0.f;
    for (int p = ps + es; p < pe; p += 8) {
        float ea = ea_sorted[(size_t)p * EDGE_IN + k];
        float y0 = y_sorted[(size_t)0 * N_EDGES + p];
        float y1 = y_sorted[(size_t)1 * N_EDGES + p];
        float y2 = y_sorted[(size_t)2 * N_EDGES + p];
        float y3 = y_sorted[(size_t)3 * N_EDGES + p];
        a0 += y0 * ea; a1 += y1 * ea; a2 += y2 * ea; a3 += y3 * ea;
        s0 += y0; s1 += y1; s2 += y2; s3 += y3;
    }
#pragma unroll
    for (int m = 8; m <= 32; m <<= 1) {
        a0 += __shfl_xor(a0, m, 64); a1 += __shfl_xor(a1, m, 64);
        a2 += __shfl_xor(a2, m, 64); a3 += __shfl_xor(a3, m, 64);
        s0 += __shfl_xor(s0, m, 64); s1 += __shfl_xor(s1, m, 64);
        s2 += __shfl_xor(s2, m, 64); s3 += __shfl_xor(s3, m, 64);
    }
    if (lane < 8) {
        agg8[((size_t)0 * N_NODES + n) * 8 + k] = a0;
        agg8[((size_t)1 * N_NODES + n) * 8 + k] = a1;
        agg8[((size_t)2 * N_NODES + n) * 8 + k] = a2;
        agg8[((size_t)3 * N_NODES + n) * 8 + k] = a3;
    }
    if (lane == 0) {
        sy_arr[(size_t)0 * N_NODES + n] = s0;
        sy_arr[(size_t)1 * N_NODES + n] = s1;
        sy_arr[(size_t)2 * N_NODES + n] = s2;
        sy_arr[(size_t)3 * N_NODES + n] = s3;
    }
}

// ---------------- h0 = x @ node_w + node_b  (bf16 only) ----------------------
__global__ void node_encode_k(const float* __restrict__ x, const float* __restrict__ nw,
                              const float* __restrict__ nb,
                              unsigned short* __restrict__ h16) {
    int idx = blockIdx.x * 256 + threadIdx.x;
    if (idx >= N_NODES * HID) return;
    int n = idx >> 7, c = idx & 127;
    float acc = nb[c];
#pragma unroll
    for (int k = 0; k < NODE_IN; ++k) acc += x[n * NODE_IN + k] * nw[k * HID + c];
    h16[idx] = f2b(acc);
}

// ---------------- gather (bf16 h): wave per node, 8-deep unroll --------------
__global__ __launch_bounds__(256) void gather16_k(
    const int* __restrict__ row_ptr, const int* __restrict__ sorted_src,
    const float* __restrict__ y_l, const unsigned short* __restrict__ h16,
    unsigned int* __restrict__ gh16) {
    int lane = threadIdx.x & 63;
    int n = (blockIdx.x * 256 + threadIdx.x) >> 6;
    int ps = row_ptr[n], pe = row_ptr[n + 1];
    float a0 = 0.f, a1 = 0.f;
    int p = ps;
    for (; p + 7 < pe; p += 8) {
        int s[8];
        float y[8];
        unsigned int v[8];
#pragma unroll
        for (int i = 0; i < 8; ++i) { s[i] = sorted_src[p + i]; y[i] = y_l[p + i]; }
#pragma unroll
        for (int i = 0; i < 8; ++i)
            v[i] = *(const unsigned int*)(h16 + (size_t)s[i] * HID + lane * 2);
#pragma unroll
        for (int i = 0; i < 8; ++i) {
            a0 += y[i] * b2f((unsigned short)v[i]);
            a1 += y[i] * b2f((unsigned short)(v[i] >> 16));
        }
    }
    for (; p + 3 < pe; p += 4) {
        int s[4];
        float y[4];
        unsigned int v[4];
#pragma unroll
        for (int i = 0; i < 4; ++i) { s[i] = sorted_src[p + i]; y[i] = y_l[p + i]; }
#pragma unroll
        for (int i = 0; i < 4; ++i)
            v[i] = *(const unsigned int*)(h16 + (size_t)s[i] * HID + lane * 2);
#pragma unroll
        for (int i = 0; i < 4; ++i) {
            a0 += y[i] * b2f((unsigned short)v[i]);
            a1 += y[i] * b2f((unsigned short)(v[i] >> 16));
        }
    }
    for (; p < pe; ++p) {
        float y = y_l[p];
        unsigned int v = *(const unsigned int*)(h16 + (size_t)sorted_src[p] * HID + lane * 2);
        a0 += y * b2f((unsigned short)v);
        a1 += y * b2f((unsigned short)(v >> 16));
    }
    gh16[(size_t)n * 64 + lane] = ((unsigned int)f2b(a1) << 16) | f2b(a0);
}

// ------- MFMA GEMM + epilogue, h16 in-place; final layer writes f32 out ------
// 16 nodes/block, 4 waves; wave w owns column tiles {2w, 2w+1}. Cross-wave LN
// via 512B LDS. Residual read from h16 (bf16); write h16 (layers 0..2) or
// f32 d_out (last layer).
__global__ __launch_bounds__(256) void mfma_ln_k(
    const unsigned short* __restrict__ gh16, const unsigned short* __restrict__ Wt16,
    const float* __restrict__ M_l, const float* __restrict__ cb_l,
    const float* __restrict__ agg8_l, const float* __restrict__ sy_l,
    const float* __restrict__ gm, const float* __restrict__ bt,
    unsigned short* __restrict__ h16, float* __restrict__ outF, int last) {
    __shared__ float red[4][16][2];
    const int tid = threadIdx.x;
    const int w = tid >> 6, lane = tid & 63;
    const int g = lane >> 4, c = lane & 15;
    const int nbase = blockIdx.x * 16;
    const int cf0 = w * 2;

    bf16x8 afrag[4];
#pragma unroll
    for (int kc = 0; kc < 4; ++kc)
        afrag[kc] = *(const bf16x8*)(gh16 + (size_t)(nbase + c) * HID + kc * 32 + g * 8);

    f32x4 acc[2];
#pragma unroll
    for (int t = 0; t < 2; ++t) {
        acc[t] = (f32x4){0.f, 0.f, 0.f, 0.f};
        const unsigned short* wp = Wt16 + (size_t)((cf0 + t) * 16 + c) * HID + g * 8;
#pragma unroll
        for (int kc = 0; kc < 4; ++kc) {
            bf16x8 bfrag = *(const bf16x8*)(wp + kc * 32);
            acc[t] = __builtin_amdgcn_mfma_f32_16x16x32_bf16(afrag[kc], bfrag, acc[t], 0, 0, 0);
        }
    }

    float cbv[2], gav[2], bev[2], mv[2][8];
#pragma unroll
    for (int t = 0; t < 2; ++t) {
        int ch = (cf0 + t) * 16 + c;
        cbv[t] = cb_l[ch]; gav[t] = gm[ch]; bev[t] = bt[ch];
#pragma unroll
        for (int k = 0; k < 8; ++k) mv[t][k] = M_l[k * HID + ch];
    }
#pragma unroll
    for (int r = 0; r < 4; ++r) {
        int node = nbase + 4 * g + r;
        float sy = sy_l[node];
        float4 t0 = ((const float4*)agg8_l)[(size_t)node * 2];
        float4 t1 = ((const float4*)agg8_l)[(size_t)node * 2 + 1];
        float a8[8] = {t0.x, t0.y, t0.z, t0.w, t1.x, t1.y, t1.z, t1.w};
#pragma unroll
        for (int t = 0; t < 2; ++t) {
            float v = sy * cbv[t];
#pragma unroll
            for (int k = 0; k < 8; ++k) v += a8[k] * mv[t][k];
            acc[t][r] += v;
        }
    }

    float sx[4], sq[4];
#pragma unroll
    for (int r = 0; r < 4; ++r) {
        sx[r] = acc[0][r] + acc[1][r];
        sq[r] = acc[0][r] * acc[0][r] + acc[1][r] * acc[1][r];
    }
#pragma unroll
    for (int m = 1; m <= 8; m <<= 1) {
#pragma unroll
        for (int r = 0; r < 4; ++r) {
            sx[r] += __shfl_xor(sx[r], m, 64);
            sq[r] += __shfl_xor(sq[r], m, 64);
        }
    }
    if (c == 0) {
#pragma unroll
        for (int r = 0; r < 4; ++r) {
            red[w][4 * g + r][0] = sx[r];
            red[w][4 * g + r][1] = sq[r];
        }
    }
    __syncthreads();

#pragma unroll
    for (int r = 0; r < 4; ++r) {
        int row = 4 * g + r;
        float SX = red[0][row][0] + red[1][row][0] + red[2][row][0] + red[3][row][0];
        float SQ = red[0][row][1] + red[1][row][1] + red[2][row][1] + red[3][row][1];
        float mean = SX * (1.0f / HID);
        float var = SQ * (1.0f / HID) - mean * mean;
        float rstd = rsqrtf(var + LN_EPS);
        int node = nbase + row;
#pragma unroll
        for (int t = 0; t < 2; ++t) {
            int ch = (cf0 + t) * 16 + c;
            size_t idx = (size_t)node * HID + ch;
            float d = acc[t][r] - mean;
            float o = b2f(h16[idx]) + fmaxf(d * rstd * gav[t] + bev[t], 0.f);
            if (last) outF[idx] = o;
            else      h16[idx] = f2b(o);
        }
    }
}

extern "C" void kernel_launch(void* const* d_in, const int* in_sizes, int n_in,
                              void* d_out, int out_size, void* d_ws, size_t ws_size,
                              hipStream_t stream) {
    const float* x         = (const float*)d_in[0];
    const void*  ei        = d_in[1];
    const float* edge_attr = (const float*)d_in[2];
    const float* node_w    = (const float*)d_in[3];
    const float* node_b    = (const float*)d_in[4];
    const float* edge_w    = (const float*)d_in[5];
    const float* edge_b    = (const float*)d_in[6];
    const float* lnode_w   = (const float*)d_in[7];
    const float* lnode_b   = (const float*)d_in[8];
    const float* ledge_w   = (const float*)d_in[9];
    const float* ledge_b   = (const float*)d_in[10];
    const float* adm_w     = (const float*)d_in[11];
    const float* adm_b     = (const float*)d_in[12];
    const float* gamma     = (const float*)d_in[13];
    const float* beta      = (const float*)d_in[14];
    float* h = (float*)d_out;

    char* wp = (char*)d_ws;
    auto alloc = [&](size_t bytes) -> void* {
        void* p = (void*)wp;
        wp += (bytes + 255) & ~(size_t)255;
        return p;
    };
    int*            flag       = (int*)alloc(256);
    int*            cursor     = (int*)alloc(sizeof(int) * N_NODES);
    int*            row_ptr    = (int*)alloc(sizeof(int) * (N_NODES + 1));
    int*            partials   = (int*)alloc(sizeof(int) * (SCAN_BLOCKS + 1));
    int*            sorted_src = (int*)alloc(sizeof(int) * N_EDGES);
    int*            sorted_eid = (int*)alloc(sizeof(int) * N_EDGES);
    float*          ea_sorted  = (float*)alloc(sizeof(float) * (size_t)N_EDGES * EDGE_IN);
    float*          y_sorted   = (float*)alloc(sizeof(float) * NLAYERS * N_EDGES);
    float*          agg8       = (float*)alloc(sizeof(float) * NLAYERS * N_NODES * 8);
    float*          sy_arr     = (float*)alloc(sizeof(float) * NLAYERS * N_NODES);
    float*          Mw         = (float*)alloc(sizeof(float) * NLAYERS * 8 * HID);
    float*          cbw        = (float*)alloc(sizeof(float) * NLAYERS * HID);
    float*          vw         = (float*)alloc(sizeof(float) * NLAYERS * 8);
    float*          cgate      = (float*)alloc(sizeof(float) * NLAYERS);
    unsigned short* h16        = (unsigned short*)alloc(sizeof(short) * (size_t)N_NODES * HID);
    unsigned short* gh16       = (unsigned short*)alloc(sizeof(short) * (size_t)N_NODES * HID);
    unsigned short* Wt16       = (unsigned short*)alloc(sizeof(short) * NLAYERS * HID * HID);
    (void)ws_size; (void)in_sizes; (void)n_in; (void)out_size;

    hipMemsetAsync(cursor, 0, sizeof(int) * N_NODES, stream);
    detect_i64<<<1, 256, 0, stream>>>((const int*)ei, flag);
    hist_k<<<(N_EDGES + 255) / 256, 256, 0, stream>>>(ei, flag, cursor);
    scan1_k<<<SCAN_BLOCKS, 256, 0, stream>>>(cursor, row_ptr, partials);
    scan2_k<<<1, 256, 0, stream>>>(partials);
    scan3_k<<<SCAN_BLOCKS, 256, 0, stream>>>(row_ptr, cursor, partials);
    place_k<<<(N_EDGES + 255) / 256, 256, 0, stream>>>(ei, flag, cursor, sorted_src, sorted_eid);
    precomp_all_k<<<(4864 + NLAYERS * HID * HID + 255) / 256, 256, 0, stream>>>(
        edge_w, edge_b, ledge_w, ledge_b, lnode_b, lnode_w, adm_w, adm_b,
        Mw, cbw, vw, cgate, Wt16);
    reorder_k<<<(N_EDGES + 255) / 256, 256, 0, stream>>>(sorted_eid, edge_attr,
                                                         vw, cgate, ea_sorted, y_sorted);
    node_stats_k<<<N_NODES / 4, 256, 0, stream>>>(row_ptr, ea_sorted, y_sorted,
                                                  agg8, sy_arr);
    node_encode_k<<<(N_NODES * HID + 255) / 256, 256, 0, stream>>>(x, node_w, node_b, h16);

    for (int l = 0; l < NLAYERS; ++l) {
        gather16_k<<<N_NODES / 4, 256, 0, stream>>>(
            row_ptr, sorted_src, y_sorted + (size_t)l * N_EDGES, h16, (unsigned int*)gh16);
        mfma_ln_k<<<N_NODES / 16, 256, 0, stream>>>(
            gh16, Wt16 + (size_t)l * HID * HID,
            Mw + (size_t)l * 8 * HID, cbw + (size_t)l * HID,
            agg8 + (size_t)l * N_NODES * 8, sy_arr + (size_t)l * N_NODES,
            gamma + (size_t)l * HID, beta + (size_t)l * HID,
            h16, h, (l == NLAYERS - 1) ? 1 : 0);
    }
}

// Round 11
// 356.022 us; speedup vs baseline: 1.1640x; 1.0611x over previous
//
#include <hip/hip_runtime.h>
#include <math.h>

#define N_NODES 50000
#define N_EDGES 600000
#define HID 128
#define NLAYERS 4
#define NODE_IN 16
#define EDGE_IN 8
#define LN_EPS 1e-5f
#define SCAN_BLOCKS ((N_NODES + 255) / 256)
#define ENC_BASE (4864 + NLAYERS * HID * HID)   // 70400
#define PRE_TOTAL (ENC_BASE + N_NODES * HID)

typedef short bf16x8 __attribute__((ext_vector_type(8)));
typedef float f32x4 __attribute__((ext_vector_type(4)));

__device__ __forceinline__ float b2f(unsigned short u) {
    union { unsigned int i; float f; } v; v.i = ((unsigned int)u) << 16; return v.f;
}
__device__ __forceinline__ unsigned short f2b(float x) {
    union { float f; unsigned int i; } v; v.f = x;
    unsigned int b = v.i + 0x7FFFu + ((v.i >> 16) & 1u);
    return (unsigned short)(b >> 16);
}

// ---------------- edge_index dtype detection (int32 vs int64) ----------------
__global__ void detect_i64(const int* ei, int* flag) {
    __shared__ int nz;
    if (threadIdx.x == 0) nz = 0;
    __syncthreads();
    int acc = 0;
    for (int i = threadIdx.x; i < 1024; i += blockDim.x)
        if (ei[2 * i + 1] != 0) acc = 1;
    if (acc) atomicOr(&nz, 1);
    __syncthreads();
    if (threadIdx.x == 0) *flag = (nz == 0) ? 1 : 0;
}

__device__ __forceinline__ int edge_src(const void* ei, int f, int e) {
    if (f) return (int)((const long long*)ei)[e];
    return ((const int*)ei)[e];
}
__device__ __forceinline__ int edge_dst(const void* ei, int f, int e) {
    if (f) return (int)((const long long*)ei)[N_EDGES + e];
    return ((const int*)ei)[N_EDGES + e];
}

// ---------------- CSR build ----------------
__global__ void hist_k(const void* ei, const int* flag, int* cursor) {
    int e = blockIdx.x * blockDim.x + threadIdx.x;
    if (e >= N_EDGES) return;
    int f = *flag;
    atomicAdd(&cursor[edge_dst(ei, f, e)], 1);
}

__global__ void scan1_k(const int* __restrict__ cursor, int* __restrict__ locex,
                        int* __restrict__ partials) {
    __shared__ int sd[256];
    int t = threadIdx.x, i = blockIdx.x * 256 + t;
    int v = (i < N_NODES) ? cursor[i] : 0;
    sd[t] = v;
    __syncthreads();
    for (int off = 1; off < 256; off <<= 1) {
        int x = (t >= off) ? sd[t - off] : 0;
        __syncthreads();
        sd[t] += x;
        __syncthreads();
    }
    if (i < N_NODES) locex[i] = sd[t] - v;
    if (t == 255) partials[blockIdx.x] = sd[255];
}

__global__ void scan2_k(int* partials) {
    __shared__ int sd[256];
    int t = threadIdx.x;
    int v = (t < SCAN_BLOCKS) ? partials[t] : 0;
    sd[t] = v;
    __syncthreads();
    for (int off = 1; off < 256; off <<= 1) {
        int x = (t >= off) ? sd[t - off] : 0;
        __syncthreads();
        sd[t] += x;
        __syncthreads();
    }
    if (t < SCAN_BLOCKS) partials[t] = sd[t] - v;
    if (t == 255) partials[SCAN_BLOCKS] = sd[255];
}

__global__ void scan3_k(int* __restrict__ row_ptr, int* __restrict__ cursor,
                        const int* __restrict__ partials) {
    int i = blockIdx.x * 256 + threadIdx.x;
    if (i < N_NODES) {
        int r = row_ptr[i] + partials[blockIdx.x];
        row_ptr[i] = r;
        cursor[i] = r;
    }
    if (i == N_NODES) row_ptr[N_NODES] = partials[SCAN_BLOCKS];
}

__global__ void place_k(const void* ei, const int* flag, int* cursor,
                        int* sorted_src, int* sorted_eid) {
    int e = blockIdx.x * blockDim.x + threadIdx.x;
    if (e >= N_EDGES) return;
    int f = *flag;
    int s = edge_src(ei, f, e);
    int d = edge_dst(ei, f, e);
    int pos = atomicAdd(&cursor[d], 1);
    sorted_src[pos] = s;
    sorted_eid[pos] = e;
}

// ---- merged: weight precompute + W^T bf16 + node encode (one dispatch) ------
__global__ void precomp_all_k(const float* __restrict__ edge_w, const float* __restrict__ edge_b,
                              const float* __restrict__ ledge_w, const float* __restrict__ ledge_b,
                              const float* __restrict__ lnode_b, const float* __restrict__ lnode_w,
                              const float* __restrict__ adm_w, const float* __restrict__ adm_b,
                              const float* __restrict__ x, const float* __restrict__ node_w,
                              const float* __restrict__ node_b,
                              float* __restrict__ M, float* __restrict__ cb,
                              float* __restrict__ v, float* __restrict__ cgate,
                              unsigned short* __restrict__ Wt16,
                              unsigned short* __restrict__ h16) {
    int t = blockIdx.x * 256 + threadIdx.x;
    if (t < 4096) {
        int l = t >> 10, k = (t >> 7) & 7, ch = t & 127;
        const float* lw = ledge_w + (size_t)l * HID * HID;
        float a = 0.f;
        for (int j = 0; j < HID; ++j) a += edge_w[k * HID + j] * lw[j * HID + ch];
        M[t] = a;
    } else if (t < 4608) {
        int u = t - 4096;
        int l = u >> 7, ch = u & 127;
        const float* lw = ledge_w + (size_t)l * HID * HID;
        float a = ledge_b[l * HID + ch] + lnode_b[l * HID + ch];
        for (int j = 0; j < HID; ++j) a += edge_b[j] * lw[j * HID + ch];
        cb[u] = a;
    } else if (t < 4640) {
        int u = t - 4608;
        int l = u >> 3, k = u & 7;
        float a = 0.f;
        for (int j = 0; j < HID; ++j) a += edge_w[k * HID + j] * adm_w[l * HID + j];
        v[u] = a;
    } else if (t < 4644) {
        int l = t - 4640;
        float a = adm_b[l];
        for (int j = 0; j < HID; ++j) a += edge_b[j] * adm_w[l * HID + j];
        cgate[l] = a;
    } else if (t >= 4864 && t < ENC_BASE) {
        int idx = t - 4864;
        int l = idx >> 14, r = idx & 16383, n = r >> 7, k = r & 127;
        Wt16[idx] = f2b(lnode_w[(size_t)l * HID * HID + k * HID + n]);
    } else if (t >= ENC_BASE && t < PRE_TOTAL) {
        int idx = t - ENC_BASE;
        int n = idx >> 7, c = idx & 127;
        float acc = node_b[c];
#pragma unroll
        for (int k = 0; k < NODE_IN; ++k) acc += x[n * NODE_IN + k] * node_w[k * HID + c];
        h16[idx] = f2b(acc);
    }
}

// ---------------- reorder + gates: thread per sorted position ----------------
__global__ __launch_bounds__(256) void reorder_k(
    const int* __restrict__ sorted_eid, const float* __restrict__ edge_attr,
    const float* __restrict__ vw, const float* __restrict__ cgate,
    float* __restrict__ ea_sorted, float* __restrict__ y_sorted) {
    __shared__ float sv[36];
    if (threadIdx.x < 32) sv[threadIdx.x] = vw[threadIdx.x];
    else if (threadIdx.x < 36) sv[threadIdx.x] = cgate[threadIdx.x - 32];
    __syncthreads();
    int p = blockIdx.x * 256 + threadIdx.x;
    if (p >= N_EDGES) return;
    int eid = sorted_eid[p];
    float4 a0 = ((const float4*)edge_attr)[(size_t)eid * 2];
    float4 a1 = ((const float4*)edge_attr)[(size_t)eid * 2 + 1];
    ((float4*)ea_sorted)[(size_t)p * 2] = a0;
    ((float4*)ea_sorted)[(size_t)p * 2 + 1] = a1;
#pragma unroll
    for (int l = 0; l < NLAYERS; ++l) {
        const float* vl = &sv[l * 8];
        float t = sv[32 + l];
        t += a0.x * vl[0] + a0.y * vl[1] + a0.z * vl[2] + a0.w * vl[3];
        t += a1.x * vl[4] + a1.y * vl[5] + a1.z * vl[6] + a1.w * vl[7];
        y_sorted[(size_t)l * N_EDGES + p] = 1.0f / (1.0f + __expf(-t));
    }
}

// ---------------- per-node edge stats: pure streaming, wave per node ---------
__global__ __launch_bounds__(256) void node_stats_k(
    const int* __restrict__ row_ptr, const float* __restrict__ ea_sorted,
    const float* __restrict__ y_sorted,
    float* __restrict__ agg8, float* __restrict__ sy_arr) {
    int lane = threadIdx.x & 63;
    int n = (blockIdx.x * 256 + threadIdx.x) >> 6;
    int es = lane >> 3, k = lane & 7;
    int ps = row_ptr[n], pe = row_ptr[n + 1];
    float a0 = 0.f, a1 = 0.f, a2 = 0.f, a3 = 0.f;
    float s0 = 0.f, s1 = 0.f, s2 = 0.f, s3 = 0.f;
    for (int p = ps + es; p < pe; p += 8) {
        float ea = ea_sorted[(size_t)p * EDGE_IN + k];
        float y0 = y_sorted[(size_t)0 * N_EDGES + p];
        float y1 = y_sorted[(size_t)1 * N_EDGES + p];
        float y2 = y_sorted[(size_t)2 * N_EDGES + p];
        float y3 = y_sorted[(size_t)3 * N_EDGES + p];
        a0 += y0 * ea; a1 += y1 * ea; a2 += y2 * ea; a3 += y3 * ea;
        s0 += y0; s1 += y1; s2 += y2; s3 += y3;
    }
#pragma unroll
    for (int m = 8; m <= 32; m <<= 1) {
        a0 += __shfl_xor(a0, m, 64); a1 += __shfl_xor(a1, m, 64);
        a2 += __shfl_xor(a2, m, 64); a3 += __shfl_xor(a3, m, 64);
        s0 += __shfl_xor(s0, m, 64); s1 += __shfl_xor(s1, m, 64);
        s2 += __shfl_xor(s2, m, 64); s3 += __shfl_xor(s3, m, 64);
    }
    if (lane < 8) {
        agg8[((size_t)0 * N_NODES + n) * 8 + k] = a0;
        agg8[((size_t)1 * N_NODES + n) * 8 + k] = a1;
        agg8[((size_t)2 * N_NODES + n) * 8 + k] = a2;
        agg8[((size_t)3 * N_NODES + n) * 8 + k] = a3;
    }
    if (lane == 0) {
        sy_arr[(size_t)0 * N_NODES + n] = s0;
        sy_arr[(size_t)1 * N_NODES + n] = s1;
        sy_arr[(size_t)2 * N_NODES + n] = s2;
        sy_arr[(size_t)3 * N_NODES + n] = s3;
    }
}

// ------- fused layer: gather(LDS) + MFMA + correction + LN + residual --------
// 512 thr / 8 waves / 16 nodes per block. Wave w gathers nodes {2w, 2w+1} into
// LDS (bf16-packed u32, padded stride 66). After barrier, wave w owns column
// tile cf=w: 4 MFMAs (A from LDS, B=Wt16), correction, cross-wave LN, residual
// from h16_in, write h16_out (or f32 outF on last layer).
__global__ __launch_bounds__(512, 4) void layer_fused_k(
    const int* __restrict__ row_ptr, const int* __restrict__ sorted_src,
    const float* __restrict__ y_l, const unsigned short* __restrict__ Wt16,
    const float* __restrict__ M_l, const float* __restrict__ cb_l,
    const float* __restrict__ agg8_l, const float* __restrict__ sy_l,
    const float* __restrict__ gm, const float* __restrict__ bt,
    const unsigned short* __restrict__ h16_in, unsigned short* __restrict__ h16_out,
    float* __restrict__ outF, int last) {
    __shared__ unsigned int ghs[16 * 66];
    __shared__ float red[8][16][2];
    const int wid = threadIdx.x >> 6, lane = threadIdx.x & 63;
    const int nbase = blockIdx.x * 16;

    // ---- phase 1: gather 2 nodes per wave into LDS
#pragma unroll 1
    for (int i = 0; i < 2; ++i) {
        int row = wid * 2 + i;
        int n = nbase + row;
        int ps = row_ptr[n], pe = row_ptr[n + 1];
        float a0 = 0.f, a1 = 0.f;
        int p = ps;
        for (; p + 7 < pe; p += 8) {
            int s[8];
            float y[8];
            unsigned int v[8];
#pragma unroll
            for (int j = 0; j < 8; ++j) { s[j] = sorted_src[p + j]; y[j] = y_l[p + j]; }
#pragma unroll
            for (int j = 0; j < 8; ++j)
                v[j] = *(const unsigned int*)(h16_in + (size_t)s[j] * HID + lane * 2);
#pragma unroll
            for (int j = 0; j < 8; ++j) {
                a0 += y[j] * b2f((unsigned short)v[j]);
                a1 += y[j] * b2f((unsigned short)(v[j] >> 16));
            }
        }
        for (; p + 3 < pe; p += 4) {
            int s[4];
            float y[4];
            unsigned int v[4];
#pragma unroll
            for (int j = 0; j < 4; ++j) { s[j] = sorted_src[p + j]; y[j] = y_l[p + j]; }
#pragma unroll
            for (int j = 0; j < 4; ++j)
                v[j] = *(const unsigned int*)(h16_in + (size_t)s[j] * HID + lane * 2);
#pragma unroll
            for (int j = 0; j < 4; ++j) {
                a0 += y[j] * b2f((unsigned short)v[j]);
                a1 += y[j] * b2f((unsigned short)(v[j] >> 16));
            }
        }
        for (; p < pe; ++p) {
            float y = y_l[p];
            unsigned int v = *(const unsigned int*)(h16_in + (size_t)sorted_src[p] * HID + lane * 2);
            a0 += y * b2f((unsigned short)v);
            a1 += y * b2f((unsigned short)(v >> 16));
        }
        ghs[row * 66 + lane] = ((unsigned int)f2b(a1) << 16) | f2b(a0);
    }
    __syncthreads();

    // ---- phase 2: MFMA on column tile cf = wid
    const int g = lane >> 4, c = lane & 15;
    const int cf = wid;
    bf16x8 afrag[4];
#pragma unroll
    for (int kc = 0; kc < 4; ++kc) {
        union { unsigned int q[4]; bf16x8 v; } u;
        int base = c * 66 + kc * 16 + g * 4;
#pragma unroll
        for (int j = 0; j < 4; ++j) u.q[j] = ghs[base + j];
        afrag[kc] = u.v;
    }
    f32x4 acc = (f32x4){0.f, 0.f, 0.f, 0.f};
    {
        const unsigned short* wp = Wt16 + (size_t)(cf * 16 + c) * HID + g * 8;
#pragma unroll
        for (int kc = 0; kc < 4; ++kc) {
            bf16x8 bfrag = *(const bf16x8*)(wp + kc * 32);
            acc = __builtin_amdgcn_mfma_f32_16x16x32_bf16(afrag[kc], bfrag, acc, 0, 0, 0);
        }
    }

    // correction: + sy*cb + agg8 @ M
    const int ch = cf * 16 + c;
    float cbv = cb_l[ch], gav = gm[ch], bev = bt[ch];
    float mv[8];
#pragma unroll
    for (int k = 0; k < 8; ++k) mv[k] = M_l[k * HID + ch];
#pragma unroll
    for (int r = 0; r < 4; ++r) {
        int node = nbase + 4 * g + r;
        float sy = sy_l[node];
        float4 t0 = ((const float4*)agg8_l)[(size_t)node * 2];
        float4 t1 = ((const float4*)agg8_l)[(size_t)node * 2 + 1];
        float vv = sy * cbv;
        vv += t0.x * mv[0] + t0.y * mv[1] + t0.z * mv[2] + t0.w * mv[3];
        vv += t1.x * mv[4] + t1.y * mv[5] + t1.z * mv[6] + t1.w * mv[7];
        acc[r] += vv;
    }

    // LN partials over this wave's 16 channels
    float sx[4], sq[4];
#pragma unroll
    for (int r = 0; r < 4; ++r) { sx[r] = acc[r]; sq[r] = acc[r] * acc[r]; }
#pragma unroll
    for (int m = 1; m <= 8; m <<= 1) {
#pragma unroll
        for (int r = 0; r < 4; ++r) {
            sx[r] += __shfl_xor(sx[r], m, 64);
            sq[r] += __shfl_xor(sq[r], m, 64);
        }
    }
    if (c == 0) {
#pragma unroll
        for (int r = 0; r < 4; ++r) {
            red[wid][4 * g + r][0] = sx[r];
            red[wid][4 * g + r][1] = sq[r];
        }
    }
    __syncthreads();

#pragma unroll
    for (int r = 0; r < 4; ++r) {
        int row = 4 * g + r;
        float SX = 0.f, SQ = 0.f;
#pragma unroll
        for (int w2 = 0; w2 < 8; ++w2) { SX += red[w2][row][0]; SQ += red[w2][row][1]; }
        float mean = SX * (1.0f / HID);
        float var = SQ * (1.0f / HID) - mean * mean;
        float rstd = rsqrtf(var + LN_EPS);
        int node = nbase + row;
        size_t idx = (size_t)node * HID + ch;
        float d = acc[r] - mean;
        float o = b2f(h16_in[idx]) + fmaxf(d * rstd * gav + bev, 0.f);
        if (last) outF[idx] = o;
        else      h16_out[idx] = f2b(o);
    }
}

extern "C" void kernel_launch(void* const* d_in, const int* in_sizes, int n_in,
                              void* d_out, int out_size, void* d_ws, size_t ws_size,
                              hipStream_t stream) {
    const float* x         = (const float*)d_in[0];
    const void*  ei        = d_in[1];
    const float* edge_attr = (const float*)d_in[2];
    const float* node_w    = (const float*)d_in[3];
    const float* node_b    = (const float*)d_in[4];
    const float* edge_w    = (const float*)d_in[5];
    const float* edge_b    = (const float*)d_in[6];
    const float* lnode_w   = (const float*)d_in[7];
    const float* lnode_b   = (const float*)d_in[8];
    const float* ledge_w   = (const float*)d_in[9];
    const float* ledge_b   = (const float*)d_in[10];
    const float* adm_w     = (const float*)d_in[11];
    const float* adm_b     = (const float*)d_in[12];
    const float* gamma     = (const float*)d_in[13];
    const float* beta      = (const float*)d_in[14];
    float* h = (float*)d_out;

    char* wp = (char*)d_ws;
    auto alloc = [&](size_t bytes) -> void* {
        void* p = (void*)wp;
        wp += (bytes + 255) & ~(size_t)255;
        return p;
    };
    int*            flag       = (int*)alloc(256);
    int*            cursor     = (int*)alloc(sizeof(int) * N_NODES);
    int*            row_ptr    = (int*)alloc(sizeof(int) * (N_NODES + 1));
    int*            partials   = (int*)alloc(sizeof(int) * (SCAN_BLOCKS + 1));
    int*            sorted_src = (int*)alloc(sizeof(int) * N_EDGES);
    int*            sorted_eid = (int*)alloc(sizeof(int) * N_EDGES);
    float*          ea_sorted  = (float*)alloc(sizeof(float) * (size_t)N_EDGES * EDGE_IN);
    float*          y_sorted   = (float*)alloc(sizeof(float) * NLAYERS * N_EDGES);
    float*          agg8       = (float*)alloc(sizeof(float) * NLAYERS * N_NODES * 8);
    float*          sy_arr     = (float*)alloc(sizeof(float) * NLAYERS * N_NODES);
    float*          Mw         = (float*)alloc(sizeof(float) * NLAYERS * 8 * HID);
    float*          cbw        = (float*)alloc(sizeof(float) * NLAYERS * HID);
    float*          vw         = (float*)alloc(sizeof(float) * NLAYERS * 8);
    float*          cgate      = (float*)alloc(sizeof(float) * NLAYERS);
    unsigned short* h16a       = (unsigned short*)alloc(sizeof(short) * (size_t)N_NODES * HID);
    unsigned short* h16b       = (unsigned short*)alloc(sizeof(short) * (size_t)N_NODES * HID);
    unsigned short* Wt16       = (unsigned short*)alloc(sizeof(short) * NLAYERS * HID * HID);
    (void)ws_size; (void)in_sizes; (void)n_in; (void)out_size;

    hipMemsetAsync(cursor, 0, sizeof(int) * N_NODES, stream);
    detect_i64<<<1, 256, 0, stream>>>((const int*)ei, flag);
    hist_k<<<(N_EDGES + 255) / 256, 256, 0, stream>>>(ei, flag, cursor);
    scan1_k<<<SCAN_BLOCKS, 256, 0, stream>>>(cursor, row_ptr, partials);
    scan2_k<<<1, 256, 0, stream>>>(partials);
    scan3_k<<<SCAN_BLOCKS, 256, 0, stream>>>(row_ptr, cursor, partials);
    place_k<<<(N_EDGES + 255) / 256, 256, 0, stream>>>(ei, flag, cursor, sorted_src, sorted_eid);
    precomp_all_k<<<(PRE_TOTAL + 255) / 256, 256, 0, stream>>>(
        edge_w, edge_b, ledge_w, ledge_b, lnode_b, lnode_w, adm_w, adm_b,
        x, node_w, node_b, Mw, cbw, vw, cgate, Wt16, h16a);
    reorder_k<<<(N_EDGES + 255) / 256, 256, 0, stream>>>(sorted_eid, edge_attr,
                                                         vw, cgate, ea_sorted, y_sorted);
    node_stats_k<<<N_NODES / 4, 256, 0, stream>>>(row_ptr, ea_sorted, y_sorted,
                                                  agg8, sy_arr);

    unsigned short* hin = h16a;
    unsigned short* hout = h16b;
    for (int l = 0; l < NLAYERS; ++l) {
        layer_fused_k<<<N_NODES / 16, 512, 0, stream>>>(
            row_ptr, sorted_src, y_sorted + (size_t)l * N_EDGES,
            Wt16 + (size_t)l * HID * HID,
            Mw + (size_t)l * 8 * HID, cbw + (size_t)l * HID,
            agg8 + (size_t)l * N_NODES * 8, sy_arr + (size_t)l * N_NODES,
            gamma + (size_t)l * HID, beta + (size_t)l * HID,
            hin, hout, h, (l == NLAYERS - 1) ? 1 : 0);
        unsigned short* t = hin; hin = hout; hout = t;
    }
}